// Round 3
// baseline (13635.217 us; speedup 1.0000x reference)
//
#include <hip/hip_runtime.h>

#define TT 2048
#define BB 512
#define II 5
#define HH 64

__device__ __forceinline__ float sigm(float v)   { return 1.0f / (1.0f + __expf(-v)); }
__device__ __forceinline__ float tanh_f(float v) { return 1.0f - 2.0f / (1.0f + __expf(2.0f * v)); }

// Keep a value opaque so the compiler cannot rematerialize it from memory:
#define KEEP(v) asm volatile("" : "+v"(v))

__global__ __launch_bounds__(256)
__attribute__((amdgpu_waves_per_eu(2, 2)))   // pin occupancy target: 2 waves/EU -> 256-VGPR budget, no spill
void lstm2_kernel(
    const float* __restrict__ x,
    const float* __restrict__ W_ih0, const float* __restrict__ W_hh0,
    const float* __restrict__ b_ih0, const float* __restrict__ b_hh0,
    const float* __restrict__ W_ih1, const float* __restrict__ W_hh1,
    const float* __restrict__ b_ih1, const float* __restrict__ b_hh1,
    const float* __restrict__ W_out, const float* __restrict__ b_out,
    float* __restrict__ out)
{
    const int t = threadIdx.x;      // gate row 0..255
    const int b = blockIdx.x;       // batch element
    const int gate = t >> 6;        // 0=i 1=f 2=g 3=o

    __shared__ __align__(16) float act0[256];   // layer-0 gates of step s
    __shared__ __align__(16) float act1[256];   // layer-1 gates of step s-1
    __shared__ __align__(16) float h1s[HH];
    __shared__ __align__(16) float h2s[HH];

    // ---- load this row's weights into registers (held for all 2048 steps) ----
    float wih0[II];
    #pragma unroll
    for (int k = 0; k < II; ++k) wih0[k] = W_ih0[t * II + k];
    const float bias0 = b_ih0[t] + b_hh0[t];
    const float bias1 = b_ih1[t] + b_hh1[t];

    float4 whh0[16], wih1[16], whh1[16];
    {
        const float4* p0 = (const float4*)(W_hh0 + t * HH);
        const float4* p1 = (const float4*)(W_ih1 + t * HH);
        const float4* p2 = (const float4*)(W_hh1 + t * HH);
        #pragma unroll
        for (int k = 0; k < 16; ++k) { whh0[k] = p0[k]; wih1[k] = p1[k]; whh1[k] = p2[k]; }
    }
    #pragma unroll
    for (int k = 0; k < 16; ++k) {
        KEEP(whh0[k].x); KEEP(whh0[k].y); KEEP(whh0[k].z); KEEP(whh0[k].w);
        KEEP(wih1[k].x); KEEP(wih1[k].y); KEEP(wih1[k].z); KEEP(wih1[k].w);
        KEEP(whh1[k].x); KEEP(whh1[k].y); KEEP(whh1[k].z); KEEP(whh1[k].w);
    }
    #pragma unroll
    for (int k = 0; k < II; ++k) KEEP(wih0[k]);

    float c1 = 0.0f, c2 = 0.0f;
    if (t < HH) { h1s[t] = 0.0f; h2s[t] = 0.0f; }
    __syncthreads();

    const float* xb = x + b * II;   // x[(s*BB + b)*II + k]
    float xc[II];
    #pragma unroll
    for (int k = 0; k < II; ++k) xc[k] = xb[k];

    // Pipelined schedule: iteration s computes gates0[s] and gates1[s-1],
    // then updates h1<-step s and h2<-step s-1. Same math as reference,
    // but one h1 broadcast serves both matrices and only 2 barriers/step.
    for (int s = 0; s <= TT; ++s) {
        // prefetch next x (wave-uniform scalar loads)
        float xn[II];
        {
            int sn = (s + 1 < TT) ? (s + 1) : (TT - 1);
            const float* xnp = xb + (size_t)sn * (BB * II);
            #pragma unroll
            for (int k = 0; k < II; ++k) xn[k] = xnp[k];
        }

        // even/odd split accumulators (dep chains of 32, not 64)
        float a0a = bias0, a0b = 0.0f;
        #pragma unroll
        for (int k = 0; k < II; ++k) a0a = fmaf(xc[k], wih0[k], a0a);
        float a1a = bias1, a1b = 0.0f;

        #pragma unroll
        for (int k = 0; k < 8; ++k) {
            float4 h1e = ((const float4*)h1s)[2 * k];
            float4 h1o = ((const float4*)h1s)[2 * k + 1];
            float4 h2e = ((const float4*)h2s)[2 * k];
            float4 h2o = ((const float4*)h2s)[2 * k + 1];

            a0a = fmaf(h1e.x, whh0[2*k].x, a0a);   a0b = fmaf(h1o.x, whh0[2*k+1].x, a0b);
            a0a = fmaf(h1e.y, whh0[2*k].y, a0a);   a0b = fmaf(h1o.y, whh0[2*k+1].y, a0b);
            a0a = fmaf(h1e.z, whh0[2*k].z, a0a);   a0b = fmaf(h1o.z, whh0[2*k+1].z, a0b);
            a0a = fmaf(h1e.w, whh0[2*k].w, a0a);   a0b = fmaf(h1o.w, whh0[2*k+1].w, a0b);

            a1a = fmaf(h1e.x, wih1[2*k].x, a1a);   a1b = fmaf(h1o.x, wih1[2*k+1].x, a1b);
            a1a = fmaf(h1e.y, wih1[2*k].y, a1a);   a1b = fmaf(h1o.y, wih1[2*k+1].y, a1b);
            a1a = fmaf(h1e.z, wih1[2*k].z, a1a);   a1b = fmaf(h1o.z, wih1[2*k+1].z, a1b);
            a1a = fmaf(h1e.w, wih1[2*k].w, a1a);   a1b = fmaf(h1o.w, wih1[2*k+1].w, a1b);

            a1a = fmaf(h2e.x, whh1[2*k].x, a1a);   a1b = fmaf(h2o.x, whh1[2*k+1].x, a1b);
            a1a = fmaf(h2e.y, whh1[2*k].y, a1a);   a1b = fmaf(h2o.y, whh1[2*k+1].y, a1b);
            a1a = fmaf(h2e.z, whh1[2*k].z, a1a);   a1b = fmaf(h2o.z, whh1[2*k+1].z, a1b);
            a1a = fmaf(h2e.w, whh1[2*k].w, a1a);   a1b = fmaf(h2o.w, whh1[2*k+1].w, a1b);
        }
        float acc0 = a0a + a0b;
        float acc1 = a1a + a1b;

        act0[t] = (gate == 2) ? tanh_f(acc0) : sigm(acc0);
        act1[t] = (gate == 2) ? tanh_f(acc1) : sigm(acc1);
        __syncthreads();                        // A: both gate sets ready

        if (t < HH) {
            if (s < TT) {                       // layer-0 state update (step s)
                float iv = act0[t], fv = act0[HH + t], gv = act0[2 * HH + t], ov = act0[3 * HH + t];
                c1 = fv * c1 + iv * gv;
                h1s[t] = ov * tanh_f(c1);
            }
            if (s >= 1) {                       // layer-1 state update (step s-1)
                float iv = act1[t], fv = act1[HH + t], gv = act1[2 * HH + t], ov = act1[3 * HH + t];
                c2 = fv * c2 + iv * gv;
                h2s[t] = ov * tanh_f(c2);
            }
        }
        __syncthreads();                        // B: h1s/h2s ready

        #pragma unroll
        for (int k = 0; k < II; ++k) xc[k] = xn[k];
    }

    // ---- final projection: out[b] = h2[TT-1] . W_out + b_out ----
    if (t < HH) {
        float v = h2s[t] * W_out[t];
        #pragma unroll
        for (int off = 32; off > 0; off >>= 1) v += __shfl_xor(v, off);
        if (t == 0) out[b] = v + b_out[0];
    }
}

extern "C" void kernel_launch(void* const* d_in, const int* in_sizes, int n_in,
                              void* d_out, int out_size, void* d_ws, size_t ws_size,
                              hipStream_t stream) {
    const float* x     = (const float*)d_in[0];
    const float* W_ih0 = (const float*)d_in[1];
    const float* W_hh0 = (const float*)d_in[2];
    const float* b_ih0 = (const float*)d_in[3];
    const float* b_hh0 = (const float*)d_in[4];
    const float* W_ih1 = (const float*)d_in[5];
    const float* W_hh1 = (const float*)d_in[6];
    const float* b_ih1 = (const float*)d_in[7];
    const float* b_hh1 = (const float*)d_in[8];
    const float* W_out = (const float*)d_in[9];
    const float* b_out = (const float*)d_in[10];
    float* out = (float*)d_out;

    lstm2_kernel<<<dim3(BB), dim3(256), 0, stream>>>(
        x, W_ih0, W_hh0, b_ih0, b_hh0, W_ih1, W_hh1, b_ih1, b_hh1, W_out, b_out, out);
}

// Round 4
// 9449.610 us; speedup vs baseline: 1.4429x; 1.4429x over previous
//
#include <hip/hip_runtime.h>

#define TT 2048
#define BB 512
#define II 5
#define HH 64
#define NTHR 768   // 3 groups x 256 threads

__device__ __forceinline__ float sigm(float v)   { return 1.0f / (1.0f + __expf(-v)); }
__device__ __forceinline__ float tanh_f(float v) { return 1.0f - 2.0f / (1.0f + __expf(2.0f * v)); }

// Design: 256 blocks (1/CU), each handles batch elems {2b, 2b+1}.
// 3 groups of 256 threads; each thread holds ONE 64-float weight row in
// registers (~110 VGPR total -- stays under the allocator's demonstrated
// 128-VGPR comfort zone; R2/R3 proved >128 never materializes, only spills).
//   group 0: layer-0 row r:  W_ih0[r,:] (5) + W_hh0[r,:] (64)  -> act0 (pre-activated)
//   group 1: W_ih1[r,:]  -> partial pB
//   group 2: W_hh1[r,:]  -> partial pC
// Pipelined schedule (verified in R3): iter s computes gates0[s] and
// gates1[s-1]; update phase writes h1[s], h2[s-1]. 2 barriers/step.
__global__ __launch_bounds__(NTHR, 3) void lstm2_kernel(
    const float* __restrict__ x,
    const float* __restrict__ W_ih0, const float* __restrict__ W_hh0,
    const float* __restrict__ b_ih0, const float* __restrict__ b_hh0,
    const float* __restrict__ W_ih1, const float* __restrict__ W_hh1,
    const float* __restrict__ b_ih1, const float* __restrict__ b_hh1,
    const float* __restrict__ W_out, const float* __restrict__ b_out,
    float* __restrict__ out)
{
    const int tid = threadIdx.x;
    const int g   = tid >> 8;        // 0,1,2
    const int r   = tid & 255;       // gate row within group
    const int blk = blockIdx.x;

    __shared__ __align__(16) float h1s[2][HH];
    __shared__ __align__(16) float h2s[2][HH];
    __shared__ __align__(16) float act0[2][256];   // layer-0 gates, activated
    __shared__ __align__(16) float pB[2][256];     // Wih1 . h1 (+bias1)
    __shared__ __align__(16) float pC[2][256];     // Whh1 . h2

    // ---- one weight row per thread ----
    const float* Wrow = (g == 0) ? (W_hh0 + r * HH)
                      : (g == 1) ? (W_ih1 + r * HH)
                                 : (W_hh1 + r * HH);
    float4 w[16];
    #pragma unroll
    for (int k = 0; k < 16; ++k) w[k] = ((const float4*)Wrow)[k];

    float wih0[II];
    float bias0 = 0.0f, bias1 = 0.0f;
    if (g == 0) {
        #pragma unroll
        for (int k = 0; k < II; ++k) wih0[k] = W_ih0[r * II + k];
        bias0 = b_ih0[r] + b_hh0[r];
    } else if (g == 1) {
        bias1 = b_ih1[r] + b_hh1[r];
    }

    float c1 = 0.0f, c2 = 0.0f;
    if (tid < 2 * HH) { ((float*)h1s)[tid] = 0.0f; ((float*)h2s)[tid] = 0.0f; }

    const float* xb0 = x + (size_t)(2 * blk + 0) * II;
    const float* xb1 = x + (size_t)(2 * blk + 1) * II;

    // xdot for iter 0 (group A only)
    float xd0 = 0.0f, xd1 = 0.0f;
    if (g == 0) {
        #pragma unroll
        for (int k = 0; k < II; ++k) {
            xd0 = fmaf(xb0[k], wih0[k], xd0);
            xd1 = fmaf(xb1[k], wih0[k], xd1);
        }
    }
    __syncthreads();

    const int gate = r >> 6;   // 0=i 1=f 2=g 3=o

    for (int s = 0; s <= TT; ++s) {
        // issue next-step x loads early; consumed at end of FMA phase
        float xl0[II], xl1[II];
        if (g == 0) {
            const int sn = (s + 1 < TT) ? (s + 1) : (TT - 1);
            const float* p0 = xb0 + (size_t)sn * (BB * II);
            const float* p1 = xb1 + (size_t)sn * (BB * II);
            #pragma unroll
            for (int k = 0; k < II; ++k) { xl0[k] = p0[k]; xl1[k] = p1[k]; }
        }

        // ---- dot products against broadcast h (both batch elems) ----
        const float4* hp0 = (g == 2) ? (const float4*)h2s[0] : (const float4*)h1s[0];
        const float4* hp1 = (g == 2) ? (const float4*)h2s[1] : (const float4*)h1s[1];
        float d0a = 0.0f, d0b = 0.0f, d1a = 0.0f, d1b = 0.0f;
        #pragma unroll
        for (int k = 0; k < 8; ++k) {
            float4 he0 = hp0[2 * k], ho0 = hp0[2 * k + 1];
            float4 he1 = hp1[2 * k], ho1 = hp1[2 * k + 1];
            d0a = fmaf(he0.x, w[2*k].x, d0a);   d0b = fmaf(ho0.x, w[2*k+1].x, d0b);
            d0a = fmaf(he0.y, w[2*k].y, d0a);   d0b = fmaf(ho0.y, w[2*k+1].y, d0b);
            d0a = fmaf(he0.z, w[2*k].z, d0a);   d0b = fmaf(ho0.z, w[2*k+1].z, d0b);
            d0a = fmaf(he0.w, w[2*k].w, d0a);   d0b = fmaf(ho0.w, w[2*k+1].w, d0b);
            d1a = fmaf(he1.x, w[2*k].x, d1a);   d1b = fmaf(ho1.x, w[2*k+1].x, d1b);
            d1a = fmaf(he1.y, w[2*k].y, d1a);   d1b = fmaf(ho1.y, w[2*k+1].y, d1b);
            d1a = fmaf(he1.z, w[2*k].z, d1a);   d1b = fmaf(ho1.z, w[2*k+1].z, d1b);
            d1a = fmaf(he1.w, w[2*k].w, d1a);   d1b = fmaf(ho1.w, w[2*k+1].w, d1b);
        }
        float d0 = d0a + d0b, d1 = d1a + d1b;

        if (g == 0) {
            d0 += bias0 + xd0;
            d1 += bias0 + xd1;
            act0[0][r] = (gate == 2) ? tanh_f(d0) : sigm(d0);
            act0[1][r] = (gate == 2) ? tanh_f(d1) : sigm(d1);
            // fold next-step xdot now (loads had the whole dot phase to land)
            float a0 = 0.0f, a1 = 0.0f;
            #pragma unroll
            for (int k = 0; k < II; ++k) {
                a0 = fmaf(xl0[k], wih0[k], a0);
                a1 = fmaf(xl1[k], wih0[k], a1);
            }
            xd0 = a0; xd1 = a1;
        } else if (g == 1) {
            pB[0][r] = d0 + bias1;
            pB[1][r] = d1 + bias1;
        } else {
            pC[0][r] = d0;
            pC[1][r] = d1;
        }
        __syncthreads();                 // A: gates0 + layer-1 partials ready

        // ---- state update: group A's 4 waves (one per SIMD).
        // waves 0,2 -> elem 0; waves 1,3 -> elem 1 (redundant same-value writes, benign)
        if (g == 0) {
            const int e = (tid >> 6) & 1;
            const int l = tid & 63;
            if (s < TT) {
                float iv = act0[e][l],        fv = act0[e][64 + l];
                float gv = act0[e][128 + l],  ov = act0[e][192 + l];
                c1 = fmaf(fv, c1, iv * gv);
                h1s[e][l] = ov * tanh_f(c1);
            }
            if (s >= 1) {
                float bi = pB[e][l]       + pC[e][l];
                float bf = pB[e][64 + l]  + pC[e][64 + l];
                float bg = pB[e][128 + l] + pC[e][128 + l];
                float bo = pB[e][192 + l] + pC[e][192 + l];
                float iv = sigm(bi), fv = sigm(bf), gv = tanh_f(bg), ov = sigm(bo);
                c2 = fmaf(fv, c2, iv * gv);
                h2s[e][l] = ov * tanh_f(c2);
            }
        }
        __syncthreads();                 // B: h1s/h2s ready
    }

    // ---- final projection: out[2b+e] = h2 . W_out + b_out ----
    if (tid < 2 * HH) {
        const int e = tid >> 6, l = tid & 63;
        float v = h2s[e][l] * W_out[l];
        #pragma unroll
        for (int off = 32; off > 0; off >>= 1) v += __shfl_xor(v, off);
        if (l == 0) out[2 * blk + e] = v + b_out[0];
    }
}

extern "C" void kernel_launch(void* const* d_in, const int* in_sizes, int n_in,
                              void* d_out, int out_size, void* d_ws, size_t ws_size,
                              hipStream_t stream) {
    const float* x     = (const float*)d_in[0];
    const float* W_ih0 = (const float*)d_in[1];
    const float* W_hh0 = (const float*)d_in[2];
    const float* b_ih0 = (const float*)d_in[3];
    const float* b_hh0 = (const float*)d_in[4];
    const float* W_ih1 = (const float*)d_in[5];
    const float* W_hh1 = (const float*)d_in[6];
    const float* b_ih1 = (const float*)d_in[7];
    const float* b_hh1 = (const float*)d_in[8];
    const float* W_out = (const float*)d_in[9];
    const float* b_out = (const float*)d_in[10];
    float* out = (float*)d_out;

    lstm2_kernel<<<dim3(BB / 2), dim3(NTHR), 0, stream>>>(
        x, W_ih0, W_hh0, b_ih0, b_hh0, W_ih1, W_hh1, b_ih1, b_hh1, W_out, b_out, out);
}